// Round 14
// baseline (258.365 us; speedup 1.0000x reference)
//
#include <hip/hip_runtime.h>

// GraphSAGE forward — round 14: r13 with the gather unrolled 8-deep (8
// full-contiguous-row loads in flight per lane before any wait) to raise
// memory-level parallelism. r13 showed lvl3 latency-bound: occupancy up,
// VALUBusy down, time flat => insufficient loads in flight per wave.
//
// Hard-won invariants:
//  - Gather reads ONE full contiguous row per vmem instruction, indices
//    shfl-broadcast (r3/r4: FETCH 199-636MB when violated).
//  - Gather stays fused with level GEMM at moderate occupancy (r7 split
//    doubled HBM traffic; r10's new writer exploded write traffic 50x).
//  - NEVER replace the scalar H-phase store path (r10: 618MB writes).
//  - Scattered 4B writes cost a 64B line each -> bucketed CSR build (r9).
//  - mean_agg(h)@W == mean_agg(h@W): all four Wa folded (r11-r13, 3e-5).
//  - A-phase elided for folded levels (relu at sM store) — r13, VALUBusy
//    drop confirmed.

#define BSHIFT 9
#define MAXBUCK 256

__global__ __launch_bounds__(256) void k_zero(int4* __restrict__ p, int n4) {
    int i = blockIdx.x * 256 + threadIdx.x;
    if (i < n4) p[i] = make_int4(0, 0, 0, 0);
}

__global__ __launch_bounds__(256) void k_count(const int* __restrict__ edst,
                                               int* __restrict__ deg, int E) {
    int t = blockIdx.x * blockDim.x + threadIdx.x;
    if (t < E) atomicAdd(&deg[edst[t]], 1);
}

__global__ __launch_bounds__(256) void k_blocksum(const int* __restrict__ deg,
                                                  int* __restrict__ bsums, int N) {
    __shared__ int s[256];
    int t = threadIdx.x;
    int base = blockIdx.x * 1024 + t * 4;
    int v = 0;
#pragma unroll
    for (int j = 0; j < 4; j++) { int idx = base + j; if (idx < N) v += deg[idx]; }
    s[t] = v; __syncthreads();
    for (int o = 128; o > 0; o >>= 1) { if (t < o) s[t] += s[t + o]; __syncthreads(); }
    if (t == 0) bsums[blockIdx.x] = s[0];
}

__global__ __launch_bounds__(256) void k_scantop(int* __restrict__ bsums, int NB) {
    __shared__ int s[256];
    int t = threadIdx.x;
    int v = (t < NB) ? bsums[t] : 0;
    s[t] = v; __syncthreads();
    for (int o = 1; o < 256; o <<= 1) {
        int x = (t >= o) ? s[t - o] : 0;
        __syncthreads();
        s[t] += x;
        __syncthreads();
    }
    if (t < NB) bsums[t] = s[t] - v;
}

__global__ __launch_bounds__(256) void k_scanfinal(const int* __restrict__ deg,
                                                   const int* __restrict__ bsums,
                                                   int* __restrict__ offsets,
                                                   float* __restrict__ inv_cnt,
                                                   int N, int E) {
    __shared__ int s[256];
    int t = threadIdx.x, b = blockIdx.x;
    int base = b * 1024 + t * 4;
    int d[4]; int lsum = 0;
#pragma unroll
    for (int j = 0; j < 4; j++) { int idx = base + j; d[j] = (idx < N) ? deg[idx] : 0; lsum += d[j]; }
    s[t] = lsum; __syncthreads();
    for (int o = 1; o < 256; o <<= 1) {
        int x = (t >= o) ? s[t - o] : 0;
        __syncthreads();
        s[t] += x;
        __syncthreads();
    }
    int p = bsums[b] + s[t] - lsum;
#pragma unroll
    for (int j = 0; j < 4; j++) {
        int idx = base + j;
        if (idx < N) {
            offsets[idx] = p;
            inv_cnt[idx] = 1.0f / (float)(d[j] > 0 ? d[j] : 1);
            p += d[j];
        }
    }
    if (b == 0 && t == 0) offsets[N] = E;
}

__global__ __launch_bounds__(256) void k_binit(const int* __restrict__ offsets,
                                               int* __restrict__ bcur, int nbuck, int N) {
    int b = blockIdx.x * blockDim.x + threadIdx.x;
    if (b < nbuck) {
        int node = b << BSHIFT;
        bcur[b] = offsets[node < N ? node : N];
    }
}

__global__ __launch_bounds__(512) void k_bucket(const int* __restrict__ esrc,
                                                const int* __restrict__ edst,
                                                int* __restrict__ bcur,
                                                int2* __restrict__ staging,
                                                int nbuck, int E) {
    __shared__ int hist[MAXBUCK];
    __shared__ int bbase[MAXBUCK];
    const int t = threadIdx.x;
    const int e = blockIdx.x * 512 + t;
    int src = 0, dst = 0, b = 0;
    if (e < E) { src = esrc[e]; dst = edst[e]; b = dst >> BSHIFT; }
    for (int i = t; i < nbuck; i += 512) hist[i] = 0;
    __syncthreads();
    int rank = 0;
    if (e < E) rank = atomicAdd(&hist[b], 1);
    __syncthreads();
    for (int i = t; i < nbuck; i += 512)
        bbase[i] = hist[i] ? atomicAdd(&bcur[i], hist[i]) : 0;
    __syncthreads();
    if (e < E) staging[bbase[b] + rank] = make_int2(src, dst);
}

__global__ __launch_bounds__(512) void k_place(const int2* __restrict__ staging,
                                               const int* __restrict__ offsets,
                                               int* __restrict__ csr, int N, int E) {
    __shared__ int cur[1 << BSHIFT];
    const int t = threadIdx.x;
    const int nbase = blockIdx.x << BSHIFT;
    const int nend = min(nbase + (1 << BSHIFT), N);
    for (int i = t; i < nend - nbase; i += 512) cur[i] = offsets[nbase + i];
    __syncthreads();
    const int estart = offsets[nbase], eend = offsets[nend];
    for (int e = estart + t; e < eend; e += 512) {
        int2 pr = staging[e];
        int pos = atomicAdd(&cur[pr.y - nbase], 1);
        csr[pos] = pr.x;
    }
}

// ---- fused level body (r13) with 8-deep gather unroll ----
template <int DIN, int DMID, int DOUT, int GSIZE, bool HAS_WA>
__device__ __forceinline__ void level_body(
    const float* __restrict__ hprev, float* __restrict__ hnext,
    const int* __restrict__ offsets, const int* __restrict__ csr,
    const float* __restrict__ inv_cnt,
    const float* __restrict__ Wa, const float* __restrict__ We, int N) {
    constexpr int WAVES = 8;
    constexpr int NPG = 64 / GSIZE;
    constexpr int NPB = WAVES * NPG;
    constexpr int VG = (DIN >= 32) ? DIN / GSIZE : 1;
    static_assert(DIN < 32 || VG == 2 || VG == 4, "gather vec width");
    constexpr bool RELU_STORE = !HAS_WA;
    static_assert(HAS_WA || DIN == DMID, "folded level needs DIN==DMID");

    __shared__ float sWa[HAS_WA ? DIN * DMID : 1];
    __shared__ float sWe[DMID * DOUT];
    __shared__ alignas(16) float sM[NPB * DIN];
    __shared__ float sA[HAS_WA ? NPB * DMID : 1];

    if constexpr (HAS_WA)
        for (int i = threadIdx.x; i < DIN * DMID; i += 512) sWa[i] = Wa[i];
    for (int i = threadIdx.x; i < DMID * DOUT; i += 512) sWe[i] = We[i];
    __syncthreads();

    const int lane = threadIdx.x & 63;
    const int wid  = threadIdx.x >> 6;
    const int g    = lane / GSIZE;
    const int lg   = lane & (GSIZE - 1);
    const int slot = wid * NPG + g;
    const int srcb = g * GSIZE;
    const long stride = (long)gridDim.x * NPB;

    for (long base = (long)blockIdx.x * NPB; base < N; base += stride) {
        int node = (int)base + slot;
        if (node < N) {
            int start = offsets[node], end = offsets[node + 1];
            if constexpr (VG == 4) {
                float4 A0 = make_float4(0.f, 0.f, 0.f, 0.f);
                float4 A1 = make_float4(0.f, 0.f, 0.f, 0.f);
                float4 A2 = make_float4(0.f, 0.f, 0.f, 0.f);
                float4 A3 = make_float4(0.f, 0.f, 0.f, 0.f);
                const float4* hp = (const float4*)hprev;
                for (int bb = start; bb < end; bb += GSIZE) {
                    int cnt = min(GSIZE, end - bb);
                    int sidx = (lg < cnt) ? csr[bb + lg] : 0;
                    int i = 0;
                    for (; i + 8 <= cnt; i += 8) {   // 8 loads in flight
                        int s0 = __shfl(sidx, srcb + i);
                        int s1 = __shfl(sidx, srcb + i + 1);
                        int s2 = __shfl(sidx, srcb + i + 2);
                        int s3 = __shfl(sidx, srcb + i + 3);
                        int s4 = __shfl(sidx, srcb + i + 4);
                        int s5 = __shfl(sidx, srcb + i + 5);
                        int s6 = __shfl(sidx, srcb + i + 6);
                        int s7 = __shfl(sidx, srcb + i + 7);
                        float4 v0 = hp[(size_t)s0 * GSIZE + lg];
                        float4 v1 = hp[(size_t)s1 * GSIZE + lg];
                        float4 v2 = hp[(size_t)s2 * GSIZE + lg];
                        float4 v3 = hp[(size_t)s3 * GSIZE + lg];
                        float4 v4 = hp[(size_t)s4 * GSIZE + lg];
                        float4 v5 = hp[(size_t)s5 * GSIZE + lg];
                        float4 v6 = hp[(size_t)s6 * GSIZE + lg];
                        float4 v7 = hp[(size_t)s7 * GSIZE + lg];
                        A0.x += v0.x; A0.y += v0.y; A0.z += v0.z; A0.w += v0.w;
                        A1.x += v1.x; A1.y += v1.y; A1.z += v1.z; A1.w += v1.w;
                        A2.x += v2.x; A2.y += v2.y; A2.z += v2.z; A2.w += v2.w;
                        A3.x += v3.x; A3.y += v3.y; A3.z += v3.z; A3.w += v3.w;
                        A0.x += v4.x; A0.y += v4.y; A0.z += v4.z; A0.w += v4.w;
                        A1.x += v5.x; A1.y += v5.y; A1.z += v5.z; A1.w += v5.w;
                        A2.x += v6.x; A2.y += v6.y; A2.z += v6.z; A2.w += v6.w;
                        A3.x += v7.x; A3.y += v7.y; A3.z += v7.z; A3.w += v7.w;
                    }
                    for (; i + 4 <= cnt; i += 4) {
                        int s0 = __shfl(sidx, srcb + i);
                        int s1 = __shfl(sidx, srcb + i + 1);
                        int s2 = __shfl(sidx, srcb + i + 2);
                        int s3 = __shfl(sidx, srcb + i + 3);
                        float4 v0 = hp[(size_t)s0 * GSIZE + lg];
                        float4 v1 = hp[(size_t)s1 * GSIZE + lg];
                        float4 v2 = hp[(size_t)s2 * GSIZE + lg];
                        float4 v3 = hp[(size_t)s3 * GSIZE + lg];
                        A0.x += v0.x; A0.y += v0.y; A0.z += v0.z; A0.w += v0.w;
                        A1.x += v1.x; A1.y += v1.y; A1.z += v1.z; A1.w += v1.w;
                        A2.x += v2.x; A2.y += v2.y; A2.z += v2.z; A2.w += v2.w;
                        A3.x += v3.x; A3.y += v3.y; A3.z += v3.z; A3.w += v3.w;
                    }
                    for (; i < cnt; ++i) {
                        int s0 = __shfl(sidx, srcb + i);
                        float4 v0 = hp[(size_t)s0 * GSIZE + lg];
                        A0.x += v0.x; A0.y += v0.y; A0.z += v0.z; A0.w += v0.w;
                    }
                }
                float ic = inv_cnt[node];
                float4 r;
                r.x = ((A0.x + A1.x) + (A2.x + A3.x)) * ic;
                r.y = ((A0.y + A1.y) + (A2.y + A3.y)) * ic;
                r.z = ((A0.z + A1.z) + (A2.z + A3.z)) * ic;
                r.w = ((A0.w + A1.w) + (A2.w + A3.w)) * ic;
                if constexpr (RELU_STORE) {
                    r.x = fmaxf(r.x, 0.f); r.y = fmaxf(r.y, 0.f);
                    r.z = fmaxf(r.z, 0.f); r.w = fmaxf(r.w, 0.f);
                }
                *(float4*)&sM[slot * DIN + 4 * lg] = r;
            } else if constexpr (VG == 2) {
                float m0 = 0, m1 = 0, n0 = 0, n1 = 0, p0 = 0, p1 = 0, q0 = 0, q1 = 0;
                const float2* hp = (const float2*)hprev;
                for (int bb = start; bb < end; bb += GSIZE) {
                    int cnt = min(GSIZE, end - bb);
                    int sidx = (lg < cnt) ? csr[bb + lg] : 0;
                    int i = 0;
                    for (; i + 8 <= cnt; i += 8) {   // 8 loads in flight
                        int s0 = __shfl(sidx, srcb + i);
                        int s1 = __shfl(sidx, srcb + i + 1);
                        int s2 = __shfl(sidx, srcb + i + 2);
                        int s3 = __shfl(sidx, srcb + i + 3);
                        int s4 = __shfl(sidx, srcb + i + 4);
                        int s5 = __shfl(sidx, srcb + i + 5);
                        int s6 = __shfl(sidx, srcb + i + 6);
                        int s7 = __shfl(sidx, srcb + i + 7);
                        float2 v0 = hp[(size_t)s0 * (DIN / 2) + lg];
                        float2 v1 = hp[(size_t)s1 * (DIN / 2) + lg];
                        float2 v2 = hp[(size_t)s2 * (DIN / 2) + lg];
                        float2 v3 = hp[(size_t)s3 * (DIN / 2) + lg];
                        float2 v4 = hp[(size_t)s4 * (DIN / 2) + lg];
                        float2 v5 = hp[(size_t)s5 * (DIN / 2) + lg];
                        float2 v6 = hp[(size_t)s6 * (DIN / 2) + lg];
                        float2 v7 = hp[(size_t)s7 * (DIN / 2) + lg];
                        m0 += v0.x; m1 += v0.y;
                        n0 += v1.x; n1 += v1.y;
                        p0 += v2.x; p1 += v2.y;
                        q0 += v3.x; q1 += v3.y;
                        m0 += v4.x; m1 += v4.y;
                        n0 += v5.x; n1 += v5.y;
                        p0 += v6.x; p1 += v6.y;
                        q0 += v7.x; q1 += v7.y;
                    }
                    for (; i + 4 <= cnt; i += 4) {
                        int s0 = __shfl(sidx, srcb + i);
                        int s1 = __shfl(sidx, srcb + i + 1);
                        int s2 = __shfl(sidx, srcb + i + 2);
                        int s3 = __shfl(sidx, srcb + i + 3);
                        float2 v0 = hp[(size_t)s0 * (DIN / 2) + lg];
                        float2 v1 = hp[(size_t)s1 * (DIN / 2) + lg];
                        float2 v2 = hp[(size_t)s2 * (DIN / 2) + lg];
                        float2 v3 = hp[(size_t)s3 * (DIN / 2) + lg];
                        m0 += v0.x; m1 += v0.y;
                        n0 += v1.x; n1 += v1.y;
                        p0 += v2.x; p1 += v2.y;
                        q0 += v3.x; q1 += v3.y;
                    }
                    for (; i < cnt; ++i) {
                        int s0 = __shfl(sidx, srcb + i);
                        float2 v0 = hp[(size_t)s0 * (DIN / 2) + lg];
                        m0 += v0.x; m1 += v0.y;
                    }
                }
                float ic = inv_cnt[node];
                float fx = ((m0 + n0) + (p0 + q0)) * ic;
                float fy = ((m1 + n1) + (p1 + q1)) * ic;
                if constexpr (RELU_STORE) { fx = fmaxf(fx, 0.f); fy = fmaxf(fy, 0.f); }
                sM[slot * DIN + 2 * lg]     = fx;
                sM[slot * DIN + 2 * lg + 1] = fy;
            } else {  // DIN == 3
                float a1 = 0.f;
                for (int bb = start; bb < end; bb += GSIZE) {
                    int cnt = min(GSIZE, end - bb);
                    int sidx = (lg < cnt) ? csr[bb + lg] : 0;
                    int i = 0;
                    for (; i + 4 <= cnt; i += 4) {
                        int s0 = __shfl(sidx, srcb + i);
                        int s1 = __shfl(sidx, srcb + i + 1);
                        int s2 = __shfl(sidx, srcb + i + 2);
                        int s3 = __shfl(sidx, srcb + i + 3);
                        if (lg < DIN) {
                            a1 += hprev[(size_t)s0 * DIN + lg] + hprev[(size_t)s1 * DIN + lg]
                                + hprev[(size_t)s2 * DIN + lg] + hprev[(size_t)s3 * DIN + lg];
                        }
                    }
                    for (; i < cnt; ++i) {
                        int s0 = __shfl(sidx, srcb + i);
                        if (lg < DIN) a1 += hprev[(size_t)s0 * DIN + lg];
                    }
                }
                if (lg < DIN) {
                    float fx = a1 * inv_cnt[node];
                    if constexpr (RELU_STORE) fx = fmaxf(fx, 0.f);
                    sM[slot * DIN + lg] = fx;
                }
            }
        }
        if constexpr (HAS_WA) {
            constexpr int AO = NPG * DMID;
#pragma unroll
            for (int r = 0; r < AO / 64; ++r) {
                int oi = r * 64 + lane;
                int sl = wid * NPG + oi / DMID;
                int col = oi & (DMID - 1);
                if ((int)base + sl < N) {
                    float v = 0.f;
#pragma unroll
                    for (int k = 0; k < DIN; ++k) v += sM[sl * DIN + k] * sWa[k * DMID + col];
                    sA[sl * DMID + col] = fmaxf(v, 0.f);
                }
            }
        }
        constexpr int HO = NPG * DOUT;
#pragma unroll
        for (int r = 0; r < HO / 64; ++r) {
            int oi = r * 64 + lane;
            int sl = wid * NPG + oi / DOUT;
            int col = oi & (DOUT - 1);
            int nd = (int)base + sl;
            if (nd < N) {
                float v = 0.f;
#pragma unroll
                for (int k = 0; k < DMID; ++k) {
                    float av = HAS_WA ? sA[sl * DMID + k] : sM[sl * DIN + k];
                    v += av * sWe[k * DOUT + col];
                }
                hnext[(size_t)nd * DOUT + col] = fmaxf(v, 0.f);
            }
        }
    }
}

__global__ __launch_bounds__(512, 8) void k_lvl1(
    const float* __restrict__ hprev, float* __restrict__ hnext,
    const int* __restrict__ offsets, const int* __restrict__ csr,
    const float* __restrict__ inv_cnt, const float* __restrict__ Wa,
    const float* __restrict__ We, int N) {
    level_body<3, 32, 32, 4, true>(hprev, hnext, offsets, csr, inv_cnt, Wa, We, N);
}
__global__ __launch_bounds__(512, 8) void k_lvl2(
    const float* __restrict__ hprev, float* __restrict__ hnext,
    const int* __restrict__ offsets, const int* __restrict__ csr,
    const float* __restrict__ inv_cnt, const float* __restrict__ Wa,
    const float* __restrict__ We, int N) {
    level_body<32, 32, 64, 16, false>(hprev, hnext, offsets, csr, inv_cnt, Wa, We, N);
}
__global__ __launch_bounds__(512, 8) void k_lvl3(
    const float* __restrict__ hprev, float* __restrict__ hnext,
    const int* __restrict__ offsets, const int* __restrict__ csr,
    const float* __restrict__ inv_cnt, const float* __restrict__ Wa,
    const float* __restrict__ We, int N) {
    level_body<64, 64, 64, 16, false>(hprev, hnext, offsets, csr, inv_cnt, Wa, We, N);
}
__global__ __launch_bounds__(512, 8) void k_lvl4(
    const float* __restrict__ hprev, float* __restrict__ hnext,
    const int* __restrict__ offsets, const int* __restrict__ csr,
    const float* __restrict__ inv_cnt, const float* __restrict__ Wa,
    const float* __restrict__ We, int N) {
    level_body<32, 32, 32, 16, false>(hprev, hnext, offsets, csr, inv_cnt, Wa, We, N);
}

// Dense fold: g = h @ W, no relu.
template <int KIN, int DCO>
__global__ __launch_bounds__(256) void k_foldT(const float* __restrict__ hin,
                                               const float* __restrict__ W,
                                               float* __restrict__ gout, int N) {
    constexpr int PAD = KIN + 4;
    __shared__ float sW[KIN * DCO];
    __shared__ alignas(16) float sH[32 * PAD];
    const int t = threadIdx.x;
    const int base = blockIdx.x * 32;
    for (int i = t; i < KIN * DCO; i += 256) sW[i] = W[i];
    constexpr int RQ = KIN / 4;
    for (int idx = t; idx < 32 * RQ; idx += 256) {
        int row = idx / RQ, q = idx % RQ;
        int node = base + row;
        float4 v = (node < N) ? ((const float4*)hin)[(size_t)node * RQ + q]
                              : make_float4(0.f, 0.f, 0.f, 0.f);
        *(float4*)&sH[row * PAD + 4 * q] = v;
    }
    __syncthreads();
    constexpr int CQ = DCO / 4;
    constexpr int TILES = 32 * CQ;
#pragma unroll
    for (int j = 0; j < (TILES + 255) / 256; ++j) {
        int idx = t + j * 256;
        if (TILES % 256 == 0 || idx < TILES) {
            int row = idx / CQ, q = idx % CQ;
            int node = base + row;
            if (node < N) {
                float a0 = 0.f, a1 = 0.f, a2 = 0.f, a3 = 0.f;
#pragma unroll
                for (int k = 0; k < KIN; ++k) {
                    float mv = sH[row * PAD + k];
                    const float* w = &sW[k * DCO + 4 * q];
                    a0 += mv * w[0]; a1 += mv * w[1];
                    a2 += mv * w[2]; a3 += mv * w[3];
                }
                float4 r = make_float4(a0, a1, a2, a3);
                *(float4*)&gout[(size_t)node * DCO + 4 * q] = r;
            }
        }
    }
}

__global__ __launch_bounds__(256, 8) void k_out(const float* __restrict__ h,
                                                const int* __restrict__ nodes,
                                                const float* __restrict__ Wout,
                                                float* __restrict__ out, int B) {
    __shared__ alignas(16) float sH[32][36];
    __shared__ float sW[32 * 40];
    __shared__ int sIdx[32];
    const int t = threadIdx.x;
    const int base = blockIdx.x * 32;
    if (t < 32) sIdx[t] = (base + t < B) ? nodes[base + t] : 0;
    for (int i = t; i < 32 * 40; i += 256) sW[i] = Wout[i];
    __syncthreads();
    {
        int g = t >> 3, lg = t & 7;
        *(float4*)&sH[g][4 * lg] = ((const float4*)h)[(size_t)sIdx[g] * 8 + lg];
    }
    __syncthreads();
#pragma unroll
    for (int j = 0; j < 5; ++j) {
        int idx = t + j * 256;
        int n = idx / 40, c = idx % 40;
        if (base + n < B) {
            float s = 0.f;
#pragma unroll
            for (int k = 0; k < 32; ++k) s += sH[n][k] * sW[k * 40 + c];
            out[(size_t)(base + n) * 40 + c] = s;
        }
    }
}

extern "C" void kernel_launch(void* const* d_in, const int* in_sizes, int n_in,
                              void* d_out, int out_size, void* d_ws, size_t ws_size,
                              hipStream_t stream) {
    const float* raw  = (const float*)d_in[0];
    const int* nodes  = (const int*)d_in[1];
    const int* esrc   = (const int*)d_in[2];
    const int* edst   = (const int*)d_in[3];
    const float* Wa1 = (const float*)d_in[4];
    const float* Wa2 = (const float*)d_in[5];
    const float* Wa3 = (const float*)d_in[6];
    const float* Wa4 = (const float*)d_in[7];
    const float* We1 = (const float*)d_in[8];
    const float* We2 = (const float*)d_in[9];
    const float* We3 = (const float*)d_in[10];
    const float* We4 = (const float*)d_in[11];
    const float* Wout = (const float*)d_in[12];
    float* out = (float*)d_out;

    int N = in_sizes[1];   // 50000
    int E = in_sizes[2];   // 850000
    int B = N;
    int nbuck = (N + (1 << BSHIFT) - 1) >> BSHIFT;

    char* p = (char*)d_ws;
    auto alloc = [&](size_t bytes) -> char* {
        char* r = p;
        p += (bytes + 255) & ~(size_t)255;
        return r;
    };
    int*   deg     = (int*)alloc((size_t)N * 4);
    int*   offsets = (int*)alloc((size_t)(N + 1) * 4);
    float* inv_cnt = (float*)alloc((size_t)N * 4);
    int NB = (N + 1023) / 1024;
    int*   bsums   = (int*)alloc((size_t)NB * 4);
    int*   bcur    = (int*)alloc((size_t)MAXBUCK * 4);
    int*   csr     = (int*)alloc((size_t)E * 4);
    float* bufA    = (float*)alloc((size_t)N * 64 * 4);
    float* bufB    = (float*)alloc((size_t)N * 64 * 4);
    float* bufC    = (float*)alloc((size_t)N * 32 * 4);
    (void)ws_size; (void)n_in; (void)out_size;

    int2* staging = (int2*)bufA;

    int n4 = N / 4;
    k_zero<<<(n4 + 255) / 256, 256, 0, stream>>>((int4*)deg, n4);

    int eb256 = (E + 255) / 256;
    int eb512 = (E + 511) / 512;
    k_count<<<eb256, 256, 0, stream>>>(edst, deg, E);
    k_blocksum<<<NB, 256, 0, stream>>>(deg, bsums, N);
    k_scantop<<<1, 256, 0, stream>>>(bsums, NB);
    k_scanfinal<<<NB, 256, 0, stream>>>(deg, bsums, offsets, inv_cnt, N, E);
    k_binit<<<(nbuck + 255) / 256, 256, 0, stream>>>(offsets, bcur, nbuck, N);
    k_bucket<<<eb512, 512, 0, stream>>>(esrc, edst, bcur, staging, nbuck, E);
    k_place<<<nbuck, 512, 0, stream>>>(staging, offsets, csr, N, E);

    auto blocksFor = [](int n, int npb) {
        int b = (n + npb - 1) / npb;
        return b < 2048 ? b : 2048;
    };
    int fb = (N + 31) / 32;

    float* h1 = bufB;
    float* g1 = bufC;
    float* h2 = bufA;
    float* g2 = bufB;
    float* h3 = bufA;
    float* g3 = bufC;
    float* h4 = bufB;

    k_lvl1<<<blocksFor(N, 128), 512, 0, stream>>>(raw, h1, offsets, csr, inv_cnt, Wa1, We1, N);
    k_foldT<32, 32><<<fb, 256, 0, stream>>>(h1, Wa2, g1, N);
    k_lvl2<<<blocksFor(N, 32), 512, 0, stream>>>(g1, h2, offsets, csr, inv_cnt, nullptr, We2, N);
    k_foldT<64, 64><<<fb, 256, 0, stream>>>(h2, Wa3, g2, N);
    k_lvl3<<<blocksFor(N, 32), 512, 0, stream>>>(g2, h3, offsets, csr, inv_cnt, nullptr, We3, N);
    k_foldT<64, 32><<<fb, 256, 0, stream>>>(h3, Wa4, g3, N);
    k_lvl4<<<blocksFor(N, 32), 512, 0, stream>>>(g3, h4, offsets, csr, inv_cnt, nullptr, We4, N);

    k_out<<<(B + 31) / 32, 256, 0, stream>>>(h4, nodes, Wout, out, B);
}

// Round 15
// 244.638 us; speedup vs baseline: 1.0561x; 1.0561x over previous
//
#include <hip/hip_runtime.h>

// GraphSAGE forward — round 15 (consolidation): r12 champion byte-identical,
// plus A-phase elision (relu at sM store, H reads sM) ONLY for lvl2/lvl4
// (r13-validated at unchanged geometry). lvl3 back to its best-known r12
// config: GSIZE=32, relu-copy A-phase, 4-deep gather unroll.
//
// Hard-won invariants:
//  - Gather reads ONE full contiguous row per vmem instruction, indices
//    shfl-broadcast (r3/r4: FETCH 199-636MB when violated).
//  - Gather MLP sweet spot is 4-deep: 8-deep overflows L2/L3 retention
//    (r14: FETCH +24%, WRITE +250%, lvl3 +14%).
//  - Gather stays fused with level GEMM at moderate occupancy (r7 split
//    doubled HBM traffic).
//  - NEVER replace the scalar H-phase store path (r10: 618MB writes).
//  - Scattered 4B writes cost a 64B line each -> bucketed CSR build (r9).
//  - mean_agg(h)@W == mean_agg(h@W): all four Wa folded (r11-r14, 3e-5).

#define BSHIFT 9
#define MAXBUCK 256

__global__ __launch_bounds__(256) void k_zero(int4* __restrict__ p, int n4) {
    int i = blockIdx.x * 256 + threadIdx.x;
    if (i < n4) p[i] = make_int4(0, 0, 0, 0);
}

__global__ __launch_bounds__(256) void k_count(const int* __restrict__ edst,
                                               int* __restrict__ deg, int E) {
    int t = blockIdx.x * blockDim.x + threadIdx.x;
    if (t < E) atomicAdd(&deg[edst[t]], 1);
}

__global__ __launch_bounds__(256) void k_blocksum(const int* __restrict__ deg,
                                                  int* __restrict__ bsums, int N) {
    __shared__ int s[256];
    int t = threadIdx.x;
    int base = blockIdx.x * 1024 + t * 4;
    int v = 0;
#pragma unroll
    for (int j = 0; j < 4; j++) { int idx = base + j; if (idx < N) v += deg[idx]; }
    s[t] = v; __syncthreads();
    for (int o = 128; o > 0; o >>= 1) { if (t < o) s[t] += s[t + o]; __syncthreads(); }
    if (t == 0) bsums[blockIdx.x] = s[0];
}

__global__ __launch_bounds__(256) void k_scantop(int* __restrict__ bsums, int NB) {
    __shared__ int s[256];
    int t = threadIdx.x;
    int v = (t < NB) ? bsums[t] : 0;
    s[t] = v; __syncthreads();
    for (int o = 1; o < 256; o <<= 1) {
        int x = (t >= o) ? s[t - o] : 0;
        __syncthreads();
        s[t] += x;
        __syncthreads();
    }
    if (t < NB) bsums[t] = s[t] - v;
}

__global__ __launch_bounds__(256) void k_scanfinal(const int* __restrict__ deg,
                                                   const int* __restrict__ bsums,
                                                   int* __restrict__ offsets,
                                                   float* __restrict__ inv_cnt,
                                                   int N, int E) {
    __shared__ int s[256];
    int t = threadIdx.x, b = blockIdx.x;
    int base = b * 1024 + t * 4;
    int d[4]; int lsum = 0;
#pragma unroll
    for (int j = 0; j < 4; j++) { int idx = base + j; d[j] = (idx < N) ? deg[idx] : 0; lsum += d[j]; }
    s[t] = lsum; __syncthreads();
    for (int o = 1; o < 256; o <<= 1) {
        int x = (t >= o) ? s[t - o] : 0;
        __syncthreads();
        s[t] += x;
        __syncthreads();
    }
    int p = bsums[b] + s[t] - lsum;
#pragma unroll
    for (int j = 0; j < 4; j++) {
        int idx = base + j;
        if (idx < N) {
            offsets[idx] = p;
            inv_cnt[idx] = 1.0f / (float)(d[j] > 0 ? d[j] : 1);
            p += d[j];
        }
    }
    if (b == 0 && t == 0) offsets[N] = E;
}

__global__ __launch_bounds__(256) void k_binit(const int* __restrict__ offsets,
                                               int* __restrict__ bcur, int nbuck, int N) {
    int b = blockIdx.x * blockDim.x + threadIdx.x;
    if (b < nbuck) {
        int node = b << BSHIFT;
        bcur[b] = offsets[node < N ? node : N];
    }
}

__global__ __launch_bounds__(512) void k_bucket(const int* __restrict__ esrc,
                                                const int* __restrict__ edst,
                                                int* __restrict__ bcur,
                                                int2* __restrict__ staging,
                                                int nbuck, int E) {
    __shared__ int hist[MAXBUCK];
    __shared__ int bbase[MAXBUCK];
    const int t = threadIdx.x;
    const int e = blockIdx.x * 512 + t;
    int src = 0, dst = 0, b = 0;
    if (e < E) { src = esrc[e]; dst = edst[e]; b = dst >> BSHIFT; }
    for (int i = t; i < nbuck; i += 512) hist[i] = 0;
    __syncthreads();
    int rank = 0;
    if (e < E) rank = atomicAdd(&hist[b], 1);
    __syncthreads();
    for (int i = t; i < nbuck; i += 512)
        bbase[i] = hist[i] ? atomicAdd(&bcur[i], hist[i]) : 0;
    __syncthreads();
    if (e < E) staging[bbase[b] + rank] = make_int2(src, dst);
}

__global__ __launch_bounds__(512) void k_place(const int2* __restrict__ staging,
                                               const int* __restrict__ offsets,
                                               int* __restrict__ csr, int N, int E) {
    __shared__ int cur[1 << BSHIFT];
    const int t = threadIdx.x;
    const int nbase = blockIdx.x << BSHIFT;
    const int nend = min(nbase + (1 << BSHIFT), N);
    for (int i = t; i < nend - nbase; i += 512) cur[i] = offsets[nbase + i];
    __syncthreads();
    const int estart = offsets[nbase], eend = offsets[nend];
    for (int e = estart + t; e < eend; e += 512) {
        int2 pr = staging[e];
        int pos = atomicAdd(&cur[pr.y - nbase], 1);
        csr[pos] = pr.x;
    }
}

// ---- fused level body (r12) + optional A-phase elision (ELIDE) ----
// HAS_WA=true: lvl1 (gather -> m@Wa -> @We).
// HAS_WA=false, !ELIDE: r12 lvl3 path (gather -> relu-copy -> @We).
// HAS_WA=false, ELIDE: r13 path (relu at sM store -> @We reads sM).
template <int DIN, int DMID, int DOUT, int GSIZE, bool HAS_WA, bool ELIDE>
__device__ __forceinline__ void level_body(
    const float* __restrict__ hprev, float* __restrict__ hnext,
    const int* __restrict__ offsets, const int* __restrict__ csr,
    const float* __restrict__ inv_cnt,
    const float* __restrict__ Wa, const float* __restrict__ We, int N) {
    constexpr int WAVES = 8;
    constexpr int NPG = 64 / GSIZE;   // nodes per wave
    constexpr int NPB = WAVES * NPG;  // nodes per block
    constexpr bool V2 = (DIN == 2 * GSIZE);
    constexpr bool RELU_STORE = (!HAS_WA) && ELIDE;
    constexpr bool HAS_SA = HAS_WA || !ELIDE;
    static_assert(HAS_WA || DIN == DMID, "folded level needs DIN==DMID");

    __shared__ float sWa[HAS_WA ? DIN * DMID : 1];
    __shared__ float sWe[DMID * DOUT];
    __shared__ float sM[NPB * DIN];   // wave-private slots
    __shared__ float sA[HAS_SA ? NPB * DMID : 1];

    if constexpr (HAS_WA)
        for (int i = threadIdx.x; i < DIN * DMID; i += 512) sWa[i] = Wa[i];
    for (int i = threadIdx.x; i < DMID * DOUT; i += 512) sWe[i] = We[i];
    __syncthreads();

    const int lane = threadIdx.x & 63;
    const int wid  = threadIdx.x >> 6;
    const int g    = lane / GSIZE;
    const int lg   = lane & (GSIZE - 1);
    const int slot = wid * NPG + g;
    const int srcb = g * GSIZE;
    const long stride = (long)gridDim.x * NPB;

    for (long base = (long)blockIdx.x * NPB; base < N; base += stride) {
        int node = (int)base + slot;
        if (node < N) {
            int start = offsets[node], end = offsets[node + 1];
            float m0 = 0, m1 = 0, n0 = 0, n1 = 0, p0 = 0, p1 = 0, q0 = 0, q1 = 0;
            for (int bb = start; bb < end; bb += GSIZE) {
                int cnt = min(GSIZE, end - bb);
                int sidx = (lg < cnt) ? csr[bb + lg] : 0;
                int i = 0;
                for (; i + 4 <= cnt; i += 4) {
                    int s0 = __shfl(sidx, srcb + i);
                    int s1 = __shfl(sidx, srcb + i + 1);
                    int s2 = __shfl(sidx, srcb + i + 2);
                    int s3 = __shfl(sidx, srcb + i + 3);
                    if (V2) {
                        const float2* hp = (const float2*)hprev;
                        float2 v0 = hp[(size_t)s0 * (DIN / 2) + lg];
                        float2 v1 = hp[(size_t)s1 * (DIN / 2) + lg];
                        float2 v2 = hp[(size_t)s2 * (DIN / 2) + lg];
                        float2 v3 = hp[(size_t)s3 * (DIN / 2) + lg];
                        m0 += v0.x; m1 += v0.y;
                        n0 += v1.x; n1 += v1.y;
                        p0 += v2.x; p1 += v2.y;
                        q0 += v3.x; q1 += v3.y;
                    } else if (lg < DIN) {
                        m0 += hprev[(size_t)s0 * DIN + lg];
                        n0 += hprev[(size_t)s1 * DIN + lg];
                        p0 += hprev[(size_t)s2 * DIN + lg];
                        q0 += hprev[(size_t)s3 * DIN + lg];
                    }
                }
                for (; i < cnt; ++i) {
                    int s0 = __shfl(sidx, srcb + i);
                    if (V2) {
                        const float2* hp = (const float2*)hprev;
                        float2 v0 = hp[(size_t)s0 * (DIN / 2) + lg];
                        m0 += v0.x; m1 += v0.y;
                    } else if (lg < DIN) {
                        m0 += hprev[(size_t)s0 * DIN + lg];
                    }
                }
            }
            float ic = inv_cnt[node];
            float fx = ((m0 + n0) + (p0 + q0)) * ic;
            if (V2) {
                float fy = ((m1 + n1) + (p1 + q1)) * ic;
                if constexpr (RELU_STORE) { fx = fmaxf(fx, 0.f); fy = fmaxf(fy, 0.f); }
                sM[slot * DIN + 2 * lg]     = fx;
                sM[slot * DIN + 2 * lg + 1] = fy;
            } else if (lg < DIN) {
                if constexpr (RELU_STORE) fx = fmaxf(fx, 0.f);
                sM[slot * DIN + lg] = fx;
            }
        }
        // A-phase: GEMM (HAS_WA) or relu-copy (!HAS_WA && !ELIDE) or skipped
        if constexpr (HAS_SA) {
            constexpr int AO = NPG * DMID;
#pragma unroll
            for (int r = 0; r < AO / 64; ++r) {
                int oi = r * 64 + lane;
                int sl = wid * NPG + oi / DMID;
                int col = oi & (DMID - 1);
                if ((int)base + sl < N) {
                    if constexpr (HAS_WA) {
                        float v = 0.f;
#pragma unroll
                        for (int k = 0; k < DIN; ++k) v += sM[sl * DIN + k] * sWa[k * DMID + col];
                        sA[sl * DMID + col] = fmaxf(v, 0.f);
                    } else {
                        sA[sl * DMID + col] = fmaxf(sM[sl * DIN + col], 0.f);
                    }
                }
            }
        }
        // H-phase: h = relu(a @ We)
        constexpr int HO = NPG * DOUT;
#pragma unroll
        for (int r = 0; r < HO / 64; ++r) {
            int oi = r * 64 + lane;
            int sl = wid * NPG + oi / DOUT;
            int col = oi & (DOUT - 1);
            int nd = (int)base + sl;
            if (nd < N) {
                float v = 0.f;
#pragma unroll
                for (int k = 0; k < DMID; ++k) {
                    float av = HAS_SA ? sA[sl * DMID + k] : sM[sl * DIN + k];
                    v += av * sWe[k * DOUT + col];
                }
                hnext[(size_t)nd * DOUT + col] = fmaxf(v, 0.f);
            }
        }
    }
}

// Wrappers: lvl1 r12-identical; lvl2/lvl4 elided (r13-validated, geometry
// unchanged); lvl3 r12-identical (GSIZE=32, relu-copy).
__global__ __launch_bounds__(512, 8) void k_lvl1(
    const float* __restrict__ hprev, float* __restrict__ hnext,
    const int* __restrict__ offsets, const int* __restrict__ csr,
    const float* __restrict__ inv_cnt, const float* __restrict__ Wa,
    const float* __restrict__ We, int N) {
    level_body<3, 32, 32, 4, true, false>(hprev, hnext, offsets, csr, inv_cnt, Wa, We, N);
}
__global__ __launch_bounds__(512, 8) void k_lvl2(
    const float* __restrict__ hprev, float* __restrict__ hnext,
    const int* __restrict__ offsets, const int* __restrict__ csr,
    const float* __restrict__ inv_cnt, const float* __restrict__ Wa,
    const float* __restrict__ We, int N) {
    level_body<32, 32, 64, 16, false, true>(hprev, hnext, offsets, csr, inv_cnt, Wa, We, N);
}
__global__ __launch_bounds__(512, 8) void k_lvl3(
    const float* __restrict__ hprev, float* __restrict__ hnext,
    const int* __restrict__ offsets, const int* __restrict__ csr,
    const float* __restrict__ inv_cnt, const float* __restrict__ Wa,
    const float* __restrict__ We, int N) {
    level_body<64, 64, 64, 32, false, false>(hprev, hnext, offsets, csr, inv_cnt, Wa, We, N);
}
__global__ __launch_bounds__(512, 8) void k_lvl4(
    const float* __restrict__ hprev, float* __restrict__ hnext,
    const int* __restrict__ offsets, const int* __restrict__ csr,
    const float* __restrict__ inv_cnt, const float* __restrict__ Wa,
    const float* __restrict__ We, int N) {
    level_body<32, 32, 32, 16, false, true>(hprev, hnext, offsets, csr, inv_cnt, Wa, We, N);
}

// Dense fold: g = h @ W, no relu. 32 nodes/block; thread -> float4 of cols.
template <int KIN, int DCO>
__global__ __launch_bounds__(256) void k_foldT(const float* __restrict__ hin,
                                               const float* __restrict__ W,
                                               float* __restrict__ gout, int N) {
    constexpr int PAD = KIN + 4;
    __shared__ float sW[KIN * DCO];
    __shared__ alignas(16) float sH[32 * PAD];
    const int t = threadIdx.x;
    const int base = blockIdx.x * 32;
    for (int i = t; i < KIN * DCO; i += 256) sW[i] = W[i];
    constexpr int RQ = KIN / 4;
    for (int idx = t; idx < 32 * RQ; idx += 256) {
        int row = idx / RQ, q = idx % RQ;
        int node = base + row;
        float4 v = (node < N) ? ((const float4*)hin)[(size_t)node * RQ + q]
                              : make_float4(0.f, 0.f, 0.f, 0.f);
        *(float4*)&sH[row * PAD + 4 * q] = v;
    }
    __syncthreads();
    constexpr int CQ = DCO / 4;
    constexpr int TILES = 32 * CQ;
#pragma unroll
    for (int j = 0; j < (TILES + 255) / 256; ++j) {
        int idx = t + j * 256;
        if (TILES % 256 == 0 || idx < TILES) {
            int row = idx / CQ, q = idx % CQ;
            int node = base + row;
            if (node < N) {
                float a0 = 0.f, a1 = 0.f, a2 = 0.f, a3 = 0.f;
#pragma unroll
                for (int k = 0; k < KIN; ++k) {
                    float mv = sH[row * PAD + k];
                    const float* w = &sW[k * DCO + 4 * q];
                    a0 += mv * w[0]; a1 += mv * w[1];
                    a2 += mv * w[2]; a3 += mv * w[3];
                }
                float4 r = make_float4(a0, a1, a2, a3);
                *(float4*)&gout[(size_t)node * DCO + 4 * q] = r;
            }
        }
    }
}

// Staged output projection (unchanged).
__global__ __launch_bounds__(256, 8) void k_out(const float* __restrict__ h,
                                                const int* __restrict__ nodes,
                                                const float* __restrict__ Wout,
                                                float* __restrict__ out, int B) {
    __shared__ alignas(16) float sH[32][36];
    __shared__ float sW[32 * 40];
    __shared__ int sIdx[32];
    const int t = threadIdx.x;
    const int base = blockIdx.x * 32;
    if (t < 32) sIdx[t] = (base + t < B) ? nodes[base + t] : 0;
    for (int i = t; i < 32 * 40; i += 256) sW[i] = Wout[i];
    __syncthreads();
    {
        int g = t >> 3, lg = t & 7;
        *(float4*)&sH[g][4 * lg] = ((const float4*)h)[(size_t)sIdx[g] * 8 + lg];
    }
    __syncthreads();
#pragma unroll
    for (int j = 0; j < 5; ++j) {
        int idx = t + j * 256;
        int n = idx / 40, c = idx % 40;
        if (base + n < B) {
            float s = 0.f;
#pragma unroll
            for (int k = 0; k < 32; ++k) s += sH[n][k] * sW[k * 40 + c];
            out[(size_t)(base + n) * 40 + c] = s;
        }
    }
}

extern "C" void kernel_launch(void* const* d_in, const int* in_sizes, int n_in,
                              void* d_out, int out_size, void* d_ws, size_t ws_size,
                              hipStream_t stream) {
    const float* raw  = (const float*)d_in[0];
    const int* nodes  = (const int*)d_in[1];
    const int* esrc   = (const int*)d_in[2];
    const int* edst   = (const int*)d_in[3];
    const float* Wa1 = (const float*)d_in[4];
    const float* Wa2 = (const float*)d_in[5];
    const float* Wa3 = (const float*)d_in[6];
    const float* Wa4 = (const float*)d_in[7];
    const float* We1 = (const float*)d_in[8];
    const float* We2 = (const float*)d_in[9];
    const float* We3 = (const float*)d_in[10];
    const float* We4 = (const float*)d_in[11];
    const float* Wout = (const float*)d_in[12];
    float* out = (float*)d_out;

    int N = in_sizes[1];   // 50000
    int E = in_sizes[2];   // 850000
    int B = N;
    int nbuck = (N + (1 << BSHIFT) - 1) >> BSHIFT;

    char* p = (char*)d_ws;
    auto alloc = [&](size_t bytes) -> char* {
        char* r = p;
        p += (bytes + 255) & ~(size_t)255;
        return r;
    };
    int*   deg     = (int*)alloc((size_t)N * 4);
    int*   offsets = (int*)alloc((size_t)(N + 1) * 4);
    float* inv_cnt = (float*)alloc((size_t)N * 4);
    int NB = (N + 1023) / 1024;
    int*   bsums   = (int*)alloc((size_t)NB * 4);
    int*   bcur    = (int*)alloc((size_t)MAXBUCK * 4);
    int*   csr     = (int*)alloc((size_t)E * 4);
    float* bufA    = (float*)alloc((size_t)N * 64 * 4);
    float* bufB    = (float*)alloc((size_t)N * 64 * 4);
    float* bufC    = (float*)alloc((size_t)N * 32 * 4);
    (void)ws_size; (void)n_in; (void)out_size;

    int2* staging = (int2*)bufA;   // overlay; dead before lvl2 writes bufA

    int n4 = N / 4;
    k_zero<<<(n4 + 255) / 256, 256, 0, stream>>>((int4*)deg, n4);

    int eb256 = (E + 255) / 256;
    int eb512 = (E + 511) / 512;
    k_count<<<eb256, 256, 0, stream>>>(edst, deg, E);
    k_blocksum<<<NB, 256, 0, stream>>>(deg, bsums, N);
    k_scantop<<<1, 256, 0, stream>>>(bsums, NB);
    k_scanfinal<<<NB, 256, 0, stream>>>(deg, bsums, offsets, inv_cnt, N, E);
    k_binit<<<(nbuck + 255) / 256, 256, 0, stream>>>(offsets, bcur, nbuck, N);
    k_bucket<<<eb512, 512, 0, stream>>>(esrc, edst, bcur, staging, nbuck, E);
    k_place<<<nbuck, 512, 0, stream>>>(staging, offsets, csr, N, E);

    auto blocksFor = [](int n, int npb) {
        int b = (n + npb - 1) / npb;
        return b < 2048 ? b : 2048;
    };
    int fb = (N + 31) / 32;

    // Buffer timeline (r11/r12, proven):
    float* h1 = bufB;
    float* g1 = bufC;
    float* h2 = bufA;
    float* g2 = bufB;
    float* h3 = bufA;
    float* g3 = bufC;
    float* h4 = bufB;

    k_lvl1<<<blocksFor(N, 128), 512, 0, stream>>>(raw, h1, offsets, csr, inv_cnt, Wa1, We1, N);
    k_foldT<32, 32><<<fb, 256, 0, stream>>>(h1, Wa2, g1, N);
    k_lvl2<<<blocksFor(N, 32), 512, 0, stream>>>(g1, h2, offsets, csr, inv_cnt, nullptr, We2, N);
    k_foldT<64, 64><<<fb, 256, 0, stream>>>(h2, Wa3, g2, N);
    k_lvl3<<<blocksFor(N, 16), 512, 0, stream>>>(g2, h3, offsets, csr, inv_cnt, nullptr, We3, N);
    k_foldT<64, 32><<<fb, 256, 0, stream>>>(h3, Wa4, g3, N);
    k_lvl4<<<blocksFor(N, 32), 512, 0, stream>>>(g3, h4, offsets, csr, inv_cnt, nullptr, We4, N);

    k_out<<<(B + 31) / 32, 256, 0, stream>>>(h4, nodes, Wout, out, B);
}